// Round 4
// baseline (762.062 us; speedup 1.0000x reference)
//
#include <hip/hip_runtime.h>
#include <hip/hip_bf16.h>

typedef unsigned short u16;
typedef __attribute__((ext_vector_type(8))) short short8;
typedef __attribute__((ext_vector_type(4))) float f32x4;

#define DIM 2048
#define HID 1408
#define NE 16
#define NTOK 2048
#define TOPK_ 4
#define SHID 2816
#define CAPROWS 10240
#define MAXTILES (CAPROWS / 128)
#define AUX_IDX (2048 * 2048)

__device__ inline u16 f2bf(float f) {
  __bf16 h = (__bf16)f;                 // RNE hardware convert
  return __builtin_bit_cast(u16, h);
}

__device__ inline void gload_lds16(const void* g, void* l) {
  __builtin_amdgcn_global_load_lds(
      (const __attribute__((address_space(1))) unsigned int*)g,
      (__attribute__((address_space(3))) unsigned int*)l, 16, 0, 0);
}

// ---------------- gate phase 1: f64 logits, no atomics ----------------
__global__ __launch_bounds__(256) void gate_dots_kernel(
    const float* __restrict__ x, const float* __restrict__ gw,
    double* __restrict__ logits) {
  int t = blockIdx.x;
  const float* xt = x + (size_t)t * DIM;
  __shared__ double red[NE][4];
  int lane = threadIdx.x & 63, wid = threadIdx.x >> 6;
  for (int e = 0; e < NE; ++e) {
    const float* w = gw + e * DIM;
    double p = 0.0;
    for (int d = threadIdx.x; d < DIM; d += 256)
      p += (double)xt[d] * (double)w[d];
#pragma unroll
    for (int s = 32; s; s >>= 1) p += __shfl_xor(p, s);
    if (lane == 0) red[e][wid] = p;
  }
  __syncthreads();
  if (threadIdx.x < NE) {
    int e = threadIdx.x;
    logits[(size_t)t * NE + e] = red[e][0] + red[e][1] + red[e][2] + red[e][3];
  }
}

// ---------------- gate phase 2: per-token softmax + top-4 ----------------
__global__ __launch_bounds__(256) void topk_kernel(
    const double* __restrict__ logits,
    int* __restrict__ idxb, float* __restrict__ wtb,
    int* __restrict__ counts, float* __restrict__ ssum) {
  __shared__ int lcnt[NE];
  __shared__ float lsum[NE];
  if (threadIdx.x < NE) { lcnt[threadIdx.x] = 0; lsum[threadIdx.x] = 0.f; }
  __syncthreads();
  int t = blockIdx.x * 256 + threadIdx.x;
  int lane = threadIdx.x & 63;
  double sc[NE];
  double m = -1e300;
#pragma unroll
  for (int e = 0; e < NE; ++e) {
    sc[e] = logits[(size_t)t * NE + e];
    if (sc[e] > m) m = sc[e];
  }
  double s = 0.0;
#pragma unroll
  for (int e = 0; e < NE; ++e) { sc[e] = exp(sc[e] - m); s += sc[e]; }
  double inv = 1.0 / s;
#pragma unroll
  for (int e = 0; e < NE; ++e) sc[e] *= inv;
  unsigned used = 0;
  for (int k = 0; k < TOPK_; ++k) {
    int be = 0; double bv = -1.0;
#pragma unroll
    for (int e = 0; e < NE; ++e)
      if (!((used >> e) & 1u) && sc[e] > bv) { bv = sc[e]; be = e; }
    used |= 1u << be;
    idxb[t * TOPK_ + k] = be;
    wtb[t * TOPK_ + k] = (float)bv;     // ROUTE_SCALE = 1
    atomicAdd(&lcnt[be], 1);
  }
#pragma unroll
  for (int e = 0; e < NE; ++e) {
    float v = (float)sc[e];
#pragma unroll
    for (int sft = 32; sft; sft >>= 1) v += __shfl_xor(v, sft);
    if (lane == 0) atomicAdd(&lsum[e], v);
  }
  __syncthreads();
  if (threadIdx.x < NE) {
    atomicAdd(&counts[threadIdx.x], lcnt[threadIdx.x]);
    atomicAdd(&ssum[threadIdx.x], lsum[threadIdx.x]);
  }
}

// ---------------- segment offsets (128-padded), tile map, aux loss ----------------
__global__ __launch_bounds__(256) void setup_kernel(
    const int* __restrict__ counts, int* __restrict__ off, int* __restrict__ cap,
    const float* __restrict__ ssum, int* __restrict__ perm, float* __restrict__ pwt,
    float* __restrict__ aux_out,
    int* __restrict__ tile2e, int* __restrict__ tile2m0, int* __restrict__ ntiles) {
  if (threadIdx.x == 0) {
    int o = 0; double aux = 0.0; int nt = 0;
    for (int e = 0; e < NE; ++e) {
      off[e] = o;
      int c = (counts[e] + 127) & ~127;
      cap[e] = c;
      for (int t = 0; t < (c >> 7); ++t) {
        tile2e[nt] = e;
        tile2m0[nt] = o + t * 128;
        ++nt;
      }
      o += c;
      aux += ((double)counts[e] / (NTOK * TOPK_)) * ((double)ssum[e] / NTOK);
    }
    ntiles[0] = nt;
    aux_out[0] = (float)(NE * aux);
  }
  for (int i = threadIdx.x; i < CAPROWS; i += 256) { perm[i] = 0; pwt[i] = 0.f; }
}

__global__ __launch_bounds__(256) void scatter_kernel(
    const int* __restrict__ idxb, const float* __restrict__ wtb,
    const int* __restrict__ off, int* __restrict__ cursor,
    int* __restrict__ perm, float* __restrict__ pwt) {
  int t = blockIdx.x * 256 + threadIdx.x;
  if (t >= NTOK) return;
  for (int k = 0; k < TOPK_; ++k) {
    int e = idxb[t * TOPK_ + k];
    int s = atomicAdd(&cursor[e], 1);
    int p = off[e] + s;
    perm[p] = t;
    pwt[p] = wtb[t * TOPK_ + k];
  }
}

__global__ __launch_bounds__(256) void cvt_kernel(const float* __restrict__ x,
                                                  u16* __restrict__ xb) {
  size_t i = ((size_t)blockIdx.x * 256 + threadIdx.x) * 8;
  float4 a = *(const float4*)(x + i);
  float4 b = *(const float4*)(x + i + 4);
  union { u16 u[8]; uint4 v; } o;
  o.u[0] = f2bf(a.x); o.u[1] = f2bf(a.y); o.u[2] = f2bf(a.z); o.u[3] = f2bf(a.w);
  o.u[4] = f2bf(b.x); o.u[5] = f2bf(b.y); o.u[6] = f2bf(b.z); o.u[7] = f2bf(b.w);
  *(uint4*)(xb + i) = o.v;
}

// ---------------- GEMM v3: 128M x 64N(-per-matrix) tile, BK=64, double-buffered ----------------
// blockIdx.x = m-tile (FASTEST -> consecutive blocks share the B panel; weights read ~once from HBM)
// blockIdx.y = n-tile.  Routed GEMMs use tile2e/tile2m0 map (no empty z-slices).
// A bf16 via global_load_lds (dbuf). B f32 reg-staged (issue-early) -> cvt -> ds_write bf16.
// EPI 0 (DUAL): Cb = bf16( silu(acc1) * acc3 )
// EPI 1: C0 = acc1 (f32 store)
// EPI 2: atomicAdd(C0[perm[row]*ldc0+col], acc1 * pwt[row]) for valid rows
template <bool GATHER, bool DUAL, int EPI>
__global__ __launch_bounds__(256) void gemm2_kernel(
    const u16* __restrict__ A, int lda,
    const float* __restrict__ B1, const float* __restrict__ B3,
    int ldb, long bstride, int K,
    const int* __restrict__ tile2e, const int* __restrict__ tile2m0,
    const int* __restrict__ ntiles,
    const int* __restrict__ seg_off, const int* __restrict__ seg_cnt,
    const int* __restrict__ perm, const float* __restrict__ pwt,
    float* __restrict__ C0, int ldc0,
    u16* __restrict__ Cb, int ldcb, int Mfixed) {
  int e, m0, rowlim;
  if (tile2e) {
    if ((int)blockIdx.x >= ntiles[0]) return;
    e = tile2e[blockIdx.x];
    m0 = tile2m0[blockIdx.x];
    rowlim = seg_off[e] + seg_cnt[e];
  } else {
    e = 0;
    m0 = blockIdx.x * 128;
    if (m0 >= Mfixed) return;
    rowlim = Mfixed;
  }
  int n0 = blockIdx.y * 64;
  const float* Bb1 = B1 + (long)e * bstride;
  const float* Bb3 = DUAL ? (B3 + (long)e * bstride) : nullptr;

  __shared__ u16 As[2][128 * 64];
  __shared__ u16 Bs1[2][64 * 64];
  __shared__ u16 Bs3[DUAL ? 2 * 64 * 64 : 2];

  int tid = threadIdx.x;
  int lane = tid & 63;
  int wid = tid >> 6;
  int wr = wid >> 1, wc = wid & 1;

  f32x4 acc1[4][2], acc3[4][2];
#pragma unroll
  for (int mi = 0; mi < 4; ++mi)
#pragma unroll
    for (int ni = 0; ni < 2; ++ni) {
      acc1[mi][ni] = (f32x4){0.f, 0.f, 0.f, 0.f};
      acc3[mi][ni] = (f32x4){0.f, 0.f, 0.f, 0.f};
    }

  // A staging: thread tid -> LDS offset tid*16B (wave-uniform base + lane*16)
  int ar = tid >> 3;          // 0..31
  int ac = (tid & 7) * 8;     // bf16 col
  long abase[4];
#pragma unroll
  for (int it = 0; it < 4; ++it) {
    int row = m0 + it * 32 + ar;
    int rid = GATHER ? perm[row] : row;
    abase[it] = (long)rid * lda + ac;
  }
  // B staging: 64 rows x 64 f32; thread -> 4 float4
  int brr = tid >> 4;         // 0..15
  int bsl = (tid & 15) * 4;   // f32 col
  long bbase[4];
#pragma unroll
  for (int it = 0; it < 4; ++it)
    bbase[it] = (long)(n0 + it * 16 + brr) * ldb + bsl;

  float4 r1[4], r3[4];

  auto stageA = [&](int buf, int k0) {
#pragma unroll
    for (int it = 0; it < 4; ++it)
      gload_lds16(A + abase[it] + k0, &As[buf][(it * 32 + ar) * 64 + ac]);
  };
  auto loadB = [&](int k0) {
#pragma unroll
    for (int it = 0; it < 4; ++it) r1[it] = *(const float4*)(Bb1 + bbase[it] + k0);
    if (DUAL) {
#pragma unroll
      for (int it = 0; it < 4; ++it) r3[it] = *(const float4*)(Bb3 + bbase[it] + k0);
    }
  };
  auto writeB = [&](int buf) {
#pragma unroll
    for (int it = 0; it < 4; ++it) {
      int lo = (it * 16 + brr) * 64 + bsl;
      ushort4 o;
      o.x = f2bf(r1[it].x); o.y = f2bf(r1[it].y); o.z = f2bf(r1[it].z); o.w = f2bf(r1[it].w);
      *(ushort4*)&Bs1[buf][lo] = o;
      if (DUAL) {
        ushort4 q;
        q.x = f2bf(r3[it].x); q.y = f2bf(r3[it].y); q.z = f2bf(r3[it].z); q.w = f2bf(r3[it].w);
        *(ushort4*)&Bs3[buf * 64 * 64 + lo] = q;
      }
    }
  };

  // prologue: tile 0
  stageA(0, 0);
  loadB(0);
  writeB(0);
  __syncthreads();   // barrier auto-drains vmcnt -> As[0] complete

  int NT = K >> 6;
  for (int t = 0; t < NT; ++t) {
    int cur = t & 1, nxt = cur ^ 1;
    bool pf = (t + 1 < NT);
    if (pf) {                     // issue next-tile loads BEFORE compute (latency hides under MFMA)
      stageA(nxt, (t + 1) << 6);
      loadB((t + 1) << 6);
    }
#pragma unroll
    for (int kk = 0; kk < 64; kk += 32) {
      short8 af[4], b1f[2], b3f[2];
#pragma unroll
      for (int i = 0; i < 4; ++i)
        af[i] = *(const short8*)&As[cur][(wr * 64 + i * 16 + (lane & 15)) * 64 + kk + (lane >> 4) * 8];
#pragma unroll
      for (int i = 0; i < 2; ++i)
        b1f[i] = *(const short8*)&Bs1[cur][(wc * 32 + i * 16 + (lane & 15)) * 64 + kk + (lane >> 4) * 8];
      if (DUAL) {
#pragma unroll
        for (int i = 0; i < 2; ++i)
          b3f[i] = *(const short8*)&Bs3[cur * 64 * 64 + (wc * 32 + i * 16 + (lane & 15)) * 64 + kk + (lane >> 4) * 8];
      }
#pragma unroll
      for (int mi = 0; mi < 4; ++mi)
#pragma unroll
        for (int ni = 0; ni < 2; ++ni) {
          acc1[mi][ni] = __builtin_amdgcn_mfma_f32_16x16x32_bf16(af[mi], b1f[ni], acc1[mi][ni], 0, 0, 0);
          if (DUAL)
            acc3[mi][ni] = __builtin_amdgcn_mfma_f32_16x16x32_bf16(af[mi], b3f[ni], acc3[mi][ni], 0, 0, 0);
        }
    }
    if (pf) writeB(nxt);          // compiler waits r1/r3 here; global latency was covered by compute
    __syncthreads();              // drains A gload_lds; all waves done with As[cur]
  }

  int rbase = m0 + wr * 64 + (lane >> 4) * 4;
  int cbase = n0 + wc * 32 + (lane & 15);
#pragma unroll
  for (int mi = 0; mi < 4; ++mi) {
#pragma unroll
    for (int ni = 0; ni < 2; ++ni) {
      int col = cbase + ni * 16;
#pragma unroll
      for (int r = 0; r < 4; ++r) {
        int row = rbase + mi * 16 + r;
        float v = acc1[mi][ni][r];
        if (EPI == 0) {
          float a3 = acc3[mi][ni][r];
          float sg = v / (1.f + __expf(-v));
          Cb[(long)row * ldcb + col] = f2bf(sg * a3);
        } else if (EPI == 1) {
          C0[(long)row * ldc0 + col] = v;
        } else {
          if (row < rowlim) {
            atomicAdd(&C0[(long)perm[row] * ldc0 + col], v * pwt[row]);
          }
        }
      }
    }
  }
}

extern "C" void kernel_launch(void* const* d_in, const int* in_sizes, int n_in,
                              void* d_out, int out_size, void* d_ws, size_t ws_size,
                              hipStream_t stream) {
  (void)in_sizes; (void)n_in; (void)out_size; (void)ws_size;
  const float* x   = (const float*)d_in[0];
  const float* gw  = (const float*)d_in[1];
  const float* w1  = (const float*)d_in[2];
  const float* w2  = (const float*)d_in[3];
  const float* w3  = (const float*)d_in[4];
  const float* sw1 = (const float*)d_in[5];
  const float* sw2 = (const float*)d_in[6];
  const float* sw3 = (const float*)d_in[7];
  float* out = (float*)d_out;
  char* ws = (char*)d_ws;

  int*   counts = (int*)(ws + 0);
  int*   cursor = (int*)(ws + 64);
  int*   off    = (int*)(ws + 128);
  int*   cap    = (int*)(ws + 192);
  float* ssum   = (float*)(ws + 256);
  int*   ntiles = (int*)(ws + 512);
  int*   tile2e = (int*)(ws + 1024);
  int*   tile2m0= (int*)(ws + 2048);
  int*   idxb   = (int*)(ws + 4096);
  float* wtb    = (float*)(ws + 4096 + 32768);
  int*   perm   = (int*)(ws + 4096 + 65536);
  float* pwt    = (float*)(ws + 4096 + 65536 + 40960);
  u16*   xb     = (u16*)(ws + 262144);
  double* logits = (double*)(ws + 262144 + 8388608);                      // gate-phase scratch
  u16*   hbuf   = (u16*)(ws + 262144 + 8388608 + 57671680);               // 10240x1408 bf16
  u16*   hsb    = (u16*)(ws + 262144 + 8388608 + 57671680 + 28835840);    // 2048x2816 bf16

  hipMemsetAsync(ws, 0, 512, stream);
  gate_dots_kernel<<<dim3(NTOK), dim3(256), 0, stream>>>(x, gw, logits);
  topk_kernel<<<dim3(NTOK / 256), dim3(256), 0, stream>>>(logits, idxb, wtb, counts, ssum);
  setup_kernel<<<dim3(1), dim3(256), 0, stream>>>(counts, off, cap, ssum, perm, pwt,
                                                  out + AUX_IDX, tile2e, tile2m0, ntiles);
  scatter_kernel<<<dim3(8), dim3(256), 0, stream>>>(idxb, wtb, off, cursor, perm, pwt);
  cvt_kernel<<<dim3(2048), dim3(256), 0, stream>>>(x, xb);

  // routed h = silu(gather(x)@w1^T) * (gather(x)@w3^T)  -> bf16  [fused dual-B, m-fastest]
  gemm2_kernel<true, true, 0><<<dim3(MAXTILES, HID / 64, 1), dim3(256), 0, stream>>>(
      xb, DIM, w1, w3, DIM, (long)HID * DIM, DIM, tile2e, tile2m0, ntiles,
      off, counts, perm, pwt, nullptr, 0, hbuf, HID, 0);
  // shared hs = silu(x@sw1^T) * (x@sw3^T) -> bf16  [fused dual-B, m-fastest]
  gemm2_kernel<false, true, 0><<<dim3(NTOK / 128, SHID / 64, 1), dim3(256), 0, stream>>>(
      xb, DIM, sw1, sw3, DIM, 0, DIM, nullptr, nullptr, nullptr,
      nullptr, nullptr, nullptr, nullptr, nullptr, 0, hsb, SHID, NTOK);
  // z = hs @ sw2^T  (plain f32 store into out)
  gemm2_kernel<false, false, 1><<<dim3(NTOK / 128, DIM / 64, 1), dim3(256), 0, stream>>>(
      hsb, SHID, sw2, nullptr, SHID, 0, SHID, nullptr, nullptr, nullptr,
      nullptr, nullptr, nullptr, nullptr, out, DIM, nullptr, 0, NTOK);
  // out += (h @ w2^T) * pwt   (atomic accumulate on top of z, m-fastest)
  gemm2_kernel<false, false, 2><<<dim3(MAXTILES, DIM / 64, 1), dim3(256), 0, stream>>>(
      hbuf, HID, w2, nullptr, HID, (long)DIM * HID, HID, tile2e, tile2m0, ntiles,
      off, counts, perm, pwt, out, DIM, nullptr, 0, 0);
}

// Round 5
// 749.558 us; speedup vs baseline: 1.0167x; 1.0167x over previous
//
#include <hip/hip_runtime.h>
#include <hip/hip_bf16.h>

typedef unsigned short u16;
typedef __attribute__((ext_vector_type(8))) short short8;
typedef __attribute__((ext_vector_type(4))) float f32x4;

#define DIM 2048
#define HID 1408
#define NE 16
#define NTOK 2048
#define TOPK_ 4
#define SHID 2816
#define CAPROWS 10240
#define MAXTILES (CAPROWS / 128)
#define AUX_IDX (2048 * 2048)

__device__ inline u16 f2bf(float f) {
  __bf16 h = (__bf16)f;                 // RNE hardware convert
  return __builtin_bit_cast(u16, h);
}

__device__ inline void gload_lds16(const void* g, void* l) {
  __builtin_amdgcn_global_load_lds(
      (const __attribute__((address_space(1))) unsigned int*)g,
      (__attribute__((address_space(3))) unsigned int*)l, 16, 0, 0);
}

// ---------------- gate phase 1: f64 logits, no atomics ----------------
__global__ __launch_bounds__(256) void gate_dots_kernel(
    const float* __restrict__ x, const float* __restrict__ gw,
    double* __restrict__ logits) {
  int t = blockIdx.x;
  const float* xt = x + (size_t)t * DIM;
  __shared__ double red[NE][4];
  int lane = threadIdx.x & 63, wid = threadIdx.x >> 6;
  for (int e = 0; e < NE; ++e) {
    const float* w = gw + e * DIM;
    double p = 0.0;
    for (int d = threadIdx.x; d < DIM; d += 256)
      p += (double)xt[d] * (double)w[d];
#pragma unroll
    for (int s = 32; s; s >>= 1) p += __shfl_xor(p, s);
    if (lane == 0) red[e][wid] = p;
  }
  __syncthreads();
  if (threadIdx.x < NE) {
    int e = threadIdx.x;
    logits[(size_t)t * NE + e] = red[e][0] + red[e][1] + red[e][2] + red[e][3];
  }
}

// ---------------- gate phase 2: per-token softmax + top-4 ----------------
__global__ __launch_bounds__(256) void topk_kernel(
    const double* __restrict__ logits,
    int* __restrict__ idxb, float* __restrict__ wtb,
    int* __restrict__ counts, float* __restrict__ ssum) {
  __shared__ int lcnt[NE];
  __shared__ float lsum[NE];
  if (threadIdx.x < NE) { lcnt[threadIdx.x] = 0; lsum[threadIdx.x] = 0.f; }
  __syncthreads();
  int t = blockIdx.x * 256 + threadIdx.x;
  int lane = threadIdx.x & 63;
  double sc[NE];
  double m = -1e300;
#pragma unroll
  for (int e = 0; e < NE; ++e) {
    sc[e] = logits[(size_t)t * NE + e];
    if (sc[e] > m) m = sc[e];
  }
  double s = 0.0;
#pragma unroll
  for (int e = 0; e < NE; ++e) { sc[e] = exp(sc[e] - m); s += sc[e]; }
  double inv = 1.0 / s;
#pragma unroll
  for (int e = 0; e < NE; ++e) sc[e] *= inv;
  unsigned used = 0;
  for (int k = 0; k < TOPK_; ++k) {
    int be = 0; double bv = -1.0;
#pragma unroll
    for (int e = 0; e < NE; ++e)
      if (!((used >> e) & 1u) && sc[e] > bv) { bv = sc[e]; be = e; }
    used |= 1u << be;
    idxb[t * TOPK_ + k] = be;
    wtb[t * TOPK_ + k] = (float)bv;     // ROUTE_SCALE = 1
    atomicAdd(&lcnt[be], 1);
  }
#pragma unroll
  for (int e = 0; e < NE; ++e) {
    float v = (float)sc[e];
#pragma unroll
    for (int sft = 32; sft; sft >>= 1) v += __shfl_xor(v, sft);
    if (lane == 0) atomicAdd(&lsum[e], v);
  }
  __syncthreads();
  if (threadIdx.x < NE) {
    atomicAdd(&counts[threadIdx.x], lcnt[threadIdx.x]);
    atomicAdd(&ssum[threadIdx.x], lsum[threadIdx.x]);
  }
}

// ---------------- segment offsets (128-padded), tile map, aux loss ----------------
__global__ __launch_bounds__(256) void setup_kernel(
    const int* __restrict__ counts, int* __restrict__ off, int* __restrict__ cap,
    const float* __restrict__ ssum, int* __restrict__ perm, float* __restrict__ pwt,
    float* __restrict__ aux_out,
    int* __restrict__ tile2e, int* __restrict__ tile2m0, int* __restrict__ ntiles) {
  if (threadIdx.x == 0) {
    int o = 0; double aux = 0.0; int nt = 0;
    for (int e = 0; e < NE; ++e) {
      off[e] = o;
      int c = (counts[e] + 127) & ~127;
      cap[e] = c;
      for (int t = 0; t < (c >> 7); ++t) {
        tile2e[nt] = e;
        tile2m0[nt] = o + t * 128;
        ++nt;
      }
      o += c;
      aux += ((double)counts[e] / (NTOK * TOPK_)) * ((double)ssum[e] / NTOK);
    }
    ntiles[0] = nt;
    aux_out[0] = (float)(NE * aux);
  }
  for (int i = threadIdx.x; i < CAPROWS; i += 256) { perm[i] = 0; pwt[i] = 0.f; }
}

__global__ __launch_bounds__(256) void scatter_kernel(
    const int* __restrict__ idxb, const float* __restrict__ wtb,
    const int* __restrict__ off, int* __restrict__ cursor,
    int* __restrict__ perm, float* __restrict__ pwt) {
  int t = blockIdx.x * 256 + threadIdx.x;
  if (t >= NTOK) return;
  for (int k = 0; k < TOPK_; ++k) {
    int e = idxb[t * TOPK_ + k];
    int s = atomicAdd(&cursor[e], 1);
    int p = off[e] + s;
    perm[p] = t;
    pwt[p] = wtb[t * TOPK_ + k];
  }
}

// ---------------- generic f32 -> bf16 stream convert (grid-stride, 8 elems/thread) ----------------
__global__ __launch_bounds__(256) void cvtN_kernel(const float* __restrict__ in,
                                                   u16* __restrict__ out, long n) {
  long stride = (long)gridDim.x * 2048;
  for (long i = ((long)blockIdx.x * 256 + threadIdx.x) * 8; i < n; i += stride) {
    float4 a = *(const float4*)(in + i);
    float4 b = *(const float4*)(in + i + 4);
    union { u16 u[8]; uint4 v; } o;
    o.u[0] = f2bf(a.x); o.u[1] = f2bf(a.y); o.u[2] = f2bf(a.z); o.u[3] = f2bf(a.w);
    o.u[4] = f2bf(b.x); o.u[5] = f2bf(b.y); o.u[6] = f2bf(b.z); o.u[7] = f2bf(b.w);
    *(uint4*)(out + i) = o.v;
  }
}

// ================= GEMM v4 (primary): all-bf16, global_load_lds both operands =================
// m97 structure: 128M x 64N(-per-matrix), BK=64, single-buffered LDS (32KB), 2-barrier loop.
// blockIdx.x = m-tile (routed: via tile2e/tile2m0 map), blockIdx.y = n-tile.
// EPI 0 (DUAL): Cb = bf16( silu(acc1) * acc3 )
// EPI 1: C0 = acc1 (f32 store)
// EPI 2: atomicAdd(C0[perm[row]*ldc0+col], acc1 * pwt[row]) for valid rows
template <bool GATHER, bool DUAL, int EPI>
__global__ __launch_bounds__(256) void gemm3_kernel(
    const u16* __restrict__ A, int lda,
    const u16* __restrict__ B1, const u16* __restrict__ B3,
    int ldb, long bstride, int K,
    const int* __restrict__ tile2e, const int* __restrict__ tile2m0,
    const int* __restrict__ ntiles,
    const int* __restrict__ seg_off, const int* __restrict__ seg_cnt,
    const int* __restrict__ perm, const float* __restrict__ pwt,
    float* __restrict__ C0, int ldc0,
    u16* __restrict__ Cb, int ldcb, int Mfixed) {
  int e, m0, rowlim;
  if (tile2e) {
    if ((int)blockIdx.x >= ntiles[0]) return;
    e = tile2e[blockIdx.x];
    m0 = tile2m0[blockIdx.x];
    rowlim = seg_off[e] + seg_cnt[e];
  } else {
    e = 0;
    m0 = blockIdx.x * 128;
    if (m0 >= Mfixed) return;
    rowlim = Mfixed;
  }
  int n0 = blockIdx.y * 64;
  const u16* Bb1 = B1 + (long)e * bstride;
  const u16* Bb3 = DUAL ? (B3 + (long)e * bstride) : nullptr;

  __shared__ u16 As[128 * 64];
  __shared__ u16 Bs1[64 * 64];
  __shared__ u16 Bs3[DUAL ? 64 * 64 : 1];

  int tid = threadIdx.x;
  int lane = tid & 63;
  int wid = tid >> 6;
  int wr = wid >> 1, wc = wid & 1;

  f32x4 acc1[4][2], acc3[4][2];
#pragma unroll
  for (int mi = 0; mi < 4; ++mi)
#pragma unroll
    for (int ni = 0; ni < 2; ++ni) {
      acc1[mi][ni] = (f32x4){0.f, 0.f, 0.f, 0.f};
      acc3[mi][ni] = (f32x4){0.f, 0.f, 0.f, 0.f};
    }

  // staging geometry: thread -> 16B chunk; LDS dest is wave-uniform base + lane*16 (linear)
  int sr = tid >> 3;          // 0..31 (row within 32-row stripe)
  int sc = (tid & 7) * 8;     // bf16 col
  long abase[4];
#pragma unroll
  for (int it = 0; it < 4; ++it) {
    int row = m0 + it * 32 + sr;
    int rid = GATHER ? perm[row] : row;
    abase[it] = (long)rid * lda + sc;
  }
  long bbase[2];
#pragma unroll
  for (int it = 0; it < 2; ++it)
    bbase[it] = (long)(n0 + it * 32 + sr) * ldb + sc;

  for (int k0 = 0; k0 < K; k0 += 64) {
#pragma unroll
    for (int it = 0; it < 4; ++it)
      gload_lds16(A + abase[it] + k0, &As[(it * 32 + sr) * 64 + sc]);
#pragma unroll
    for (int it = 0; it < 2; ++it)
      gload_lds16(Bb1 + bbase[it] + k0, &Bs1[(it * 32 + sr) * 64 + sc]);
    if (DUAL) {
#pragma unroll
      for (int it = 0; it < 2; ++it)
        gload_lds16(Bb3 + bbase[it] + k0, &Bs3[(it * 32 + sr) * 64 + sc]);
    }
    __syncthreads();            // drains vmcnt -> LDS tile complete
#pragma unroll
    for (int kk = 0; kk < 64; kk += 32) {
      short8 af[4], b1f[2], b3f[2];
#pragma unroll
      for (int i = 0; i < 4; ++i)
        af[i] = *(const short8*)&As[(wr * 64 + i * 16 + (lane & 15)) * 64 + kk + (lane >> 4) * 8];
#pragma unroll
      for (int i = 0; i < 2; ++i)
        b1f[i] = *(const short8*)&Bs1[(wc * 32 + i * 16 + (lane & 15)) * 64 + kk + (lane >> 4) * 8];
      if (DUAL) {
#pragma unroll
        for (int i = 0; i < 2; ++i)
          b3f[i] = *(const short8*)&Bs3[(wc * 32 + i * 16 + (lane & 15)) * 64 + kk + (lane >> 4) * 8];
      }
#pragma unroll
      for (int mi = 0; mi < 4; ++mi)
#pragma unroll
        for (int ni = 0; ni < 2; ++ni) {
          acc1[mi][ni] = __builtin_amdgcn_mfma_f32_16x16x32_bf16(af[mi], b1f[ni], acc1[mi][ni], 0, 0, 0);
          if (DUAL)
            acc3[mi][ni] = __builtin_amdgcn_mfma_f32_16x16x32_bf16(af[mi], b3f[ni], acc3[mi][ni], 0, 0, 0);
        }
    }
    __syncthreads();            // all waves done reading before next overwrite
  }

  int rbase = m0 + wr * 64 + (lane >> 4) * 4;
  int cbase = n0 + wc * 32 + (lane & 15);
#pragma unroll
  for (int mi = 0; mi < 4; ++mi) {
#pragma unroll
    for (int ni = 0; ni < 2; ++ni) {
      int col = cbase + ni * 16;
#pragma unroll
      for (int r = 0; r < 4; ++r) {
        int row = rbase + mi * 16 + r;
        float v = acc1[mi][ni][r];
        if (EPI == 0) {
          float a3 = acc3[mi][ni][r];
          float sg = v / (1.f + __expf(-v));
          Cb[(long)row * ldcb + col] = f2bf(sg * a3);
        } else if (EPI == 1) {
          C0[(long)row * ldc0 + col] = v;
        } else {
          if (row < rowlim) {
            atomicAdd(&C0[(long)perm[row] * ldc0 + col], v * pwt[row]);
          }
        }
      }
    }
  }
}

// ================= GEMM v3 (fallback when ws too small): f32 B reg-staged =================
template <bool GATHER, bool DUAL, int EPI>
__global__ __launch_bounds__(256) void gemm2_kernel(
    const u16* __restrict__ A, int lda,
    const float* __restrict__ B1, const float* __restrict__ B3,
    int ldb, long bstride, int K,
    const int* __restrict__ tile2e, const int* __restrict__ tile2m0,
    const int* __restrict__ ntiles,
    const int* __restrict__ seg_off, const int* __restrict__ seg_cnt,
    const int* __restrict__ perm, const float* __restrict__ pwt,
    float* __restrict__ C0, int ldc0,
    u16* __restrict__ Cb, int ldcb, int Mfixed) {
  int e, m0, rowlim;
  if (tile2e) {
    if ((int)blockIdx.x >= ntiles[0]) return;
    e = tile2e[blockIdx.x];
    m0 = tile2m0[blockIdx.x];
    rowlim = seg_off[e] + seg_cnt[e];
  } else {
    e = 0;
    m0 = blockIdx.x * 128;
    if (m0 >= Mfixed) return;
    rowlim = Mfixed;
  }
  int n0 = blockIdx.y * 64;
  const float* Bb1 = B1 + (long)e * bstride;
  const float* Bb3 = DUAL ? (B3 + (long)e * bstride) : nullptr;

  __shared__ u16 As[2][128 * 64];
  __shared__ u16 Bs1[2][64 * 64];
  __shared__ u16 Bs3[DUAL ? 2 * 64 * 64 : 2];

  int tid = threadIdx.x;
  int lane = tid & 63;
  int wid = tid >> 6;
  int wr = wid >> 1, wc = wid & 1;

  f32x4 acc1[4][2], acc3[4][2];
#pragma unroll
  for (int mi = 0; mi < 4; ++mi)
#pragma unroll
    for (int ni = 0; ni < 2; ++ni) {
      acc1[mi][ni] = (f32x4){0.f, 0.f, 0.f, 0.f};
      acc3[mi][ni] = (f32x4){0.f, 0.f, 0.f, 0.f};
    }

  int ar = tid >> 3;
  int ac = (tid & 7) * 8;
  long abase[4];
#pragma unroll
  for (int it = 0; it < 4; ++it) {
    int row = m0 + it * 32 + ar;
    int rid = GATHER ? perm[row] : row;
    abase[it] = (long)rid * lda + ac;
  }
  int brr = tid >> 4;
  int bsl = (tid & 15) * 4;
  long bbase[4];
#pragma unroll
  for (int it = 0; it < 4; ++it)
    bbase[it] = (long)(n0 + it * 16 + brr) * ldb + bsl;

  float4 r1[4], r3[4];

  auto stageA = [&](int buf, int k0) {
#pragma unroll
    for (int it = 0; it < 4; ++it)
      gload_lds16(A + abase[it] + k0, &As[buf][(it * 32 + ar) * 64 + ac]);
  };
  auto loadB = [&](int k0) {
#pragma unroll
    for (int it = 0; it < 4; ++it) r1[it] = *(const float4*)(Bb1 + bbase[it] + k0);
    if (DUAL) {
#pragma unroll
      for (int it = 0; it < 4; ++it) r3[it] = *(const float4*)(Bb3 + bbase[it] + k0);
    }
  };
  auto writeB = [&](int buf) {
#pragma unroll
    for (int it = 0; it < 4; ++it) {
      int lo = (it * 16 + brr) * 64 + bsl;
      ushort4 o;
      o.x = f2bf(r1[it].x); o.y = f2bf(r1[it].y); o.z = f2bf(r1[it].z); o.w = f2bf(r1[it].w);
      *(ushort4*)&Bs1[buf][lo] = o;
      if (DUAL) {
        ushort4 q;
        q.x = f2bf(r3[it].x); q.y = f2bf(r3[it].y); q.z = f2bf(r3[it].z); q.w = f2bf(r3[it].w);
        *(ushort4*)&Bs3[buf * 64 * 64 + lo] = q;
      }
    }
  };

  stageA(0, 0);
  loadB(0);
  writeB(0);
  __syncthreads();

  int NT = K >> 6;
  for (int t = 0; t < NT; ++t) {
    int cur = t & 1, nxt = cur ^ 1;
    bool pf = (t + 1 < NT);
    if (pf) {
      stageA(nxt, (t + 1) << 6);
      loadB((t + 1) << 6);
    }
#pragma unroll
    for (int kk = 0; kk < 64; kk += 32) {
      short8 af[4], b1f[2], b3f[2];
#pragma unroll
      for (int i = 0; i < 4; ++i)
        af[i] = *(const short8*)&As[cur][(wr * 64 + i * 16 + (lane & 15)) * 64 + kk + (lane >> 4) * 8];
#pragma unroll
      for (int i = 0; i < 2; ++i)
        b1f[i] = *(const short8*)&Bs1[cur][(wc * 32 + i * 16 + (lane & 15)) * 64 + kk + (lane >> 4) * 8];
      if (DUAL) {
#pragma unroll
        for (int i = 0; i < 2; ++i)
          b3f[i] = *(const short8*)&Bs3[cur * 64 * 64 + (wc * 32 + i * 16 + (lane & 15)) * 64 + kk + (lane >> 4) * 8];
      }
#pragma unroll
      for (int mi = 0; mi < 4; ++mi)
#pragma unroll
        for (int ni = 0; ni < 2; ++ni) {
          acc1[mi][ni] = __builtin_amdgcn_mfma_f32_16x16x32_bf16(af[mi], b1f[ni], acc1[mi][ni], 0, 0, 0);
          if (DUAL)
            acc3[mi][ni] = __builtin_amdgcn_mfma_f32_16x16x32_bf16(af[mi], b3f[ni], acc3[mi][ni], 0, 0, 0);
        }
    }
    if (pf) writeB(nxt);
    __syncthreads();
  }

  int rbase = m0 + wr * 64 + (lane >> 4) * 4;
  int cbase = n0 + wc * 32 + (lane & 15);
#pragma unroll
  for (int mi = 0; mi < 4; ++mi) {
#pragma unroll
    for (int ni = 0; ni < 2; ++ni) {
      int col = cbase + ni * 16;
#pragma unroll
      for (int r = 0; r < 4; ++r) {
        int row = rbase + mi * 16 + r;
        float v = acc1[mi][ni][r];
        if (EPI == 0) {
          float a3 = acc3[mi][ni][r];
          float sg = v / (1.f + __expf(-v));
          Cb[(long)row * ldcb + col] = f2bf(sg * a3);
        } else if (EPI == 1) {
          C0[(long)row * ldc0 + col] = v;
        } else {
          if (row < rowlim) {
            atomicAdd(&C0[(long)perm[row] * ldc0 + col], v * pwt[row]);
          }
        }
      }
    }
  }
}

extern "C" void kernel_launch(void* const* d_in, const int* in_sizes, int n_in,
                              void* d_out, int out_size, void* d_ws, size_t ws_size,
                              hipStream_t stream) {
  (void)in_sizes; (void)n_in; (void)out_size;
  const float* x   = (const float*)d_in[0];
  const float* gw  = (const float*)d_in[1];
  const float* w1  = (const float*)d_in[2];
  const float* w2  = (const float*)d_in[3];
  const float* w3  = (const float*)d_in[4];
  const float* sw1 = (const float*)d_in[5];
  const float* sw2 = (const float*)d_in[6];
  const float* sw3 = (const float*)d_in[7];
  float* out = (float*)d_out;
  char* ws = (char*)d_ws;

  int*   counts = (int*)(ws + 0);
  int*   cursor = (int*)(ws + 64);
  int*   off    = (int*)(ws + 128);
  int*   cap    = (int*)(ws + 192);
  float* ssum   = (float*)(ws + 256);
  int*   ntiles = (int*)(ws + 512);
  int*   tile2e = (int*)(ws + 1024);
  int*   tile2m0= (int*)(ws + 2048);
  int*   idxb   = (int*)(ws + 4096);
  float* wtb    = (float*)(ws + 4096 + 32768);
  int*   perm   = (int*)(ws + 4096 + 65536);
  float* pwt    = (float*)(ws + 4096 + 65536 + 40960);
  u16*   xb     = (u16*)(ws + 262144);                 // 2048x2048 bf16, 8.39 MB
  double* logits = (double*)(ws + 8650752);            // 2048x16 f64, 256 KB
  u16*   hbuf   = (u16*)(ws + 16777216);               // 10240x1408 bf16, 28.8 MB
  u16*   hsb    = (u16*)(ws + 45613056);               // 2048x2816 bf16, 11.5 MB
  u16*   wbuf   = (u16*)(ws + 67108864);               // reusable bf16 weight buf, 184.5 MB

  const size_t NEEDED = 67108864ull + 184549376ull;    // 251,658,240
  bool bf16w = ws_size >= NEEDED;

  hipMemsetAsync(ws, 0, 512, stream);
  gate_dots_kernel<<<dim3(NTOK), dim3(256), 0, stream>>>(x, gw, logits);
  topk_kernel<<<dim3(NTOK / 256), dim3(256), 0, stream>>>(logits, idxb, wtb, counts, ssum);
  setup_kernel<<<dim3(1), dim3(256), 0, stream>>>(counts, off, cap, ssum, perm, pwt,
                                                  out + AUX_IDX, tile2e, tile2m0, ntiles);
  scatter_kernel<<<dim3(8), dim3(256), 0, stream>>>(idxb, wtb, off, cursor, perm, pwt);
  cvtN_kernel<<<dim3(2048), dim3(256), 0, stream>>>(x, xb, (long)NTOK * DIM);

  if (bf16w) {
    const long NW13 = (long)NE * HID * DIM;            // 46,137,344 elems per matrix
    const long NSH  = (long)SHID * DIM;                // 5,767,168 elems
    u16* wbuf2_13 = wbuf + NW13;
    u16* wbuf2_sh = wbuf + NSH;

    // routed h = silu(gather(x)@w1^T) * (gather(x)@w3^T) -> bf16
    cvtN_kernel<<<dim3(2048), dim3(256), 0, stream>>>(w1, wbuf, NW13);
    cvtN_kernel<<<dim3(2048), dim3(256), 0, stream>>>(w3, wbuf2_13, NW13);
    gemm3_kernel<true, true, 0><<<dim3(MAXTILES, HID / 64, 1), dim3(256), 0, stream>>>(
        xb, DIM, wbuf, wbuf2_13, DIM, (long)HID * DIM, DIM, tile2e, tile2m0, ntiles,
        off, counts, perm, pwt, nullptr, 0, hbuf, HID, 0);
    // shared hs = silu(x@sw1^T) * (x@sw3^T) -> bf16
    cvtN_kernel<<<dim3(2048), dim3(256), 0, stream>>>(sw1, wbuf, NSH);
    cvtN_kernel<<<dim3(2048), dim3(256), 0, stream>>>(sw3, wbuf2_sh, NSH);
    gemm3_kernel<false, true, 0><<<dim3(NTOK / 128, SHID / 64, 1), dim3(256), 0, stream>>>(
        xb, DIM, wbuf, wbuf2_sh, DIM, 0, DIM, nullptr, nullptr, nullptr,
        nullptr, nullptr, nullptr, nullptr, nullptr, 0, hsb, SHID, NTOK);
    // z = hs @ sw2^T  (f32 store into out)
    cvtN_kernel<<<dim3(2048), dim3(256), 0, stream>>>(sw2, wbuf, NSH);
    gemm3_kernel<false, false, 1><<<dim3(NTOK / 128, DIM / 64, 1), dim3(256), 0, stream>>>(
        hsb, SHID, wbuf, nullptr, SHID, 0, SHID, nullptr, nullptr, nullptr,
        nullptr, nullptr, nullptr, nullptr, out, DIM, nullptr, 0, NTOK);
    // out += (h @ w2^T) * pwt
    cvtN_kernel<<<dim3(2048), dim3(256), 0, stream>>>(w2, wbuf, NW13);
    gemm3_kernel<false, false, 2><<<dim3(MAXTILES, DIM / 64, 1), dim3(256), 0, stream>>>(
        hbuf, HID, wbuf, nullptr, HID, (long)DIM * HID, HID, tile2e, tile2m0, ntiles,
        off, counts, perm, pwt, out, DIM, nullptr, 0, 0);
  } else {
    gemm2_kernel<true, true, 0><<<dim3(MAXTILES, HID / 64, 1), dim3(256), 0, stream>>>(
        xb, DIM, w1, w3, DIM, (long)HID * DIM, DIM, tile2e, tile2m0, ntiles,
        off, counts, perm, pwt, nullptr, 0, hbuf, HID, 0);
    gemm2_kernel<false, true, 0><<<dim3(NTOK / 128, SHID / 64, 1), dim3(256), 0, stream>>>(
        xb, DIM, sw1, sw3, DIM, 0, DIM, nullptr, nullptr, nullptr,
        nullptr, nullptr, nullptr, nullptr, nullptr, 0, hsb, SHID, NTOK);
    gemm2_kernel<false, false, 1><<<dim3(NTOK / 128, DIM / 64, 1), dim3(256), 0, stream>>>(
        hsb, SHID, sw2, nullptr, SHID, 0, SHID, nullptr, nullptr, nullptr,
        nullptr, nullptr, nullptr, nullptr, out, DIM, nullptr, 0, NTOK);
    gemm2_kernel<false, false, 2><<<dim3(MAXTILES, DIM / 64, 1), dim3(256), 0, stream>>>(
        hbuf, HID, w2, nullptr, HID, (long)DIM * HID, HID, tile2e, tile2m0, ntiles,
        off, counts, perm, pwt, out, DIM, nullptr, 0, 0);
  }
}

// Round 6
// 706.565 us; speedup vs baseline: 1.0785x; 1.0608x over previous
//
#include <hip/hip_runtime.h>
#include <hip/hip_bf16.h>

typedef unsigned short u16;
typedef __attribute__((ext_vector_type(8))) short short8;
typedef __attribute__((ext_vector_type(4))) float f32x4;

#define DIM 2048
#define HID 1408
#define NE 16
#define NTOK 2048
#define TOPK_ 4
#define SHID 2816
#define CAPROWS 10240
#define MAXTILES (CAPROWS / 128)   // 80; 80 % 8 == 0 so XCD == blockIdx.x % 8
#define AUX_IDX (2048 * 2048)

__device__ inline u16 f2bf(float f) {
  __bf16 h = (__bf16)f;                 // RNE hardware convert
  return __builtin_bit_cast(u16, h);
}

__device__ inline void gload_lds16(const void* g, void* l) {
  __builtin_amdgcn_global_load_lds(
      (const __attribute__((address_space(1))) unsigned int*)g,
      (__attribute__((address_space(3))) unsigned int*)l, 16, 0, 0);
}

// ---------------- gate phase 1: f64 logits, no atomics ----------------
__global__ __launch_bounds__(256) void gate_dots_kernel(
    const float* __restrict__ x, const float* __restrict__ gw,
    double* __restrict__ logits) {
  int t = blockIdx.x;
  const float* xt = x + (size_t)t * DIM;
  __shared__ double red[NE][4];
  int lane = threadIdx.x & 63, wid = threadIdx.x >> 6;
  for (int e = 0; e < NE; ++e) {
    const float* w = gw + e * DIM;
    double p = 0.0;
    for (int d = threadIdx.x; d < DIM; d += 256)
      p += (double)xt[d] * (double)w[d];
#pragma unroll
    for (int s = 32; s; s >>= 1) p += __shfl_xor(p, s);
    if (lane == 0) red[e][wid] = p;
  }
  __syncthreads();
  if (threadIdx.x < NE) {
    int e = threadIdx.x;
    logits[(size_t)t * NE + e] = red[e][0] + red[e][1] + red[e][2] + red[e][3];
  }
}

// ---------------- gate phase 2: per-token softmax + top-4 ----------------
__global__ __launch_bounds__(256) void topk_kernel(
    const double* __restrict__ logits,
    int* __restrict__ idxb, float* __restrict__ wtb,
    int* __restrict__ counts, float* __restrict__ ssum) {
  __shared__ int lcnt[NE];
  __shared__ float lsum[NE];
  if (threadIdx.x < NE) { lcnt[threadIdx.x] = 0; lsum[threadIdx.x] = 0.f; }
  __syncthreads();
  int t = blockIdx.x * 256 + threadIdx.x;
  int lane = threadIdx.x & 63;
  double sc[NE];
  double m = -1e300;
#pragma unroll
  for (int e = 0; e < NE; ++e) {
    sc[e] = logits[(size_t)t * NE + e];
    if (sc[e] > m) m = sc[e];
  }
  double s = 0.0;
#pragma unroll
  for (int e = 0; e < NE; ++e) { sc[e] = exp(sc[e] - m); s += sc[e]; }
  double inv = 1.0 / s;
#pragma unroll
  for (int e = 0; e < NE; ++e) sc[e] *= inv;
  unsigned used = 0;
  for (int k = 0; k < TOPK_; ++k) {
    int be = 0; double bv = -1.0;
#pragma unroll
    for (int e = 0; e < NE; ++e)
      if (!((used >> e) & 1u) && sc[e] > bv) { bv = sc[e]; be = e; }
    used |= 1u << be;
    idxb[t * TOPK_ + k] = be;
    wtb[t * TOPK_ + k] = (float)bv;     // ROUTE_SCALE = 1
    atomicAdd(&lcnt[be], 1);
  }
#pragma unroll
  for (int e = 0; e < NE; ++e) {
    float v = (float)sc[e];
#pragma unroll
    for (int sft = 32; sft; sft >>= 1) v += __shfl_xor(v, sft);
    if (lane == 0) atomicAdd(&lsum[e], v);
  }
  __syncthreads();
  if (threadIdx.x < NE) {
    atomicAdd(&counts[threadIdx.x], lcnt[threadIdx.x]);
    atomicAdd(&ssum[threadIdx.x], lsum[threadIdx.x]);
  }
}

// -------- segment offsets (128-padded), XCD-grouped tile map, aux loss --------
// Tile slot for expert-ordered tile i: (i/10) + (i%10)*8  (bijective on [0,80)).
// Consecutive same-expert tiles land on the SAME XCD (slot % 8 equal), so the
// expert's weight panel is served by one coherent L2 instead of 8.
__global__ __launch_bounds__(256) void setup_kernel(
    const int* __restrict__ counts, int* __restrict__ off, int* __restrict__ cap,
    const float* __restrict__ ssum, int* __restrict__ perm, float* __restrict__ pwt,
    float* __restrict__ aux_out,
    int* __restrict__ tile2e, int* __restrict__ tile2m0) {
  for (int i = threadIdx.x; i < MAXTILES; i += 256) tile2e[i] = -1;
  __syncthreads();
  if (threadIdx.x == 0) {
    int o = 0; double aux = 0.0; int nt = 0;
    for (int e = 0; e < NE; ++e) {
      off[e] = o;
      int c = (counts[e] + 127) & ~127;
      cap[e] = c;
      for (int t = 0; t < (c >> 7); ++t) {
        int slot = (nt / 10) + (nt % 10) * 8;
        tile2e[slot] = e;
        tile2m0[slot] = o + t * 128;
        ++nt;
      }
      o += c;
      aux += ((double)counts[e] / (NTOK * TOPK_)) * ((double)ssum[e] / NTOK);
    }
    aux_out[0] = (float)(NE * aux);
  }
  for (int i = threadIdx.x; i < CAPROWS; i += 256) { perm[i] = 0; pwt[i] = 0.f; }
}

__global__ __launch_bounds__(256) void scatter_kernel(
    const int* __restrict__ idxb, const float* __restrict__ wtb,
    const int* __restrict__ off, int* __restrict__ cursor,
    int* __restrict__ perm, float* __restrict__ pwt) {
  int t = blockIdx.x * 256 + threadIdx.x;
  if (t >= NTOK) return;
  for (int k = 0; k < TOPK_; ++k) {
    int e = idxb[t * TOPK_ + k];
    int s = atomicAdd(&cursor[e], 1);
    int p = off[e] + s;
    perm[p] = t;
    pwt[p] = wtb[t * TOPK_ + k];
  }
}

// ---------------- f32 -> bf16 stream convert (for x only) ----------------
__global__ __launch_bounds__(256) void cvtN_kernel(const float* __restrict__ in,
                                                   u16* __restrict__ out, long n) {
  long stride = (long)gridDim.x * 2048;
  for (long i = ((long)blockIdx.x * 256 + threadIdx.x) * 8; i < n; i += stride) {
    float4 a = *(const float4*)(in + i);
    float4 b = *(const float4*)(in + i + 4);
    union { u16 u[8]; uint4 v; } o;
    o.u[0] = f2bf(a.x); o.u[1] = f2bf(a.y); o.u[2] = f2bf(a.z); o.u[3] = f2bf(a.w);
    o.u[4] = f2bf(b.x); o.u[5] = f2bf(b.y); o.u[6] = f2bf(b.z); o.u[7] = f2bf(b.w);
    *(uint4*)(out + i) = o.v;
  }
}

// ============ GEMM v5: A bf16 gload_lds, B f32 reg-staged->cvt->LDS ============
// 128M x 64N(-per-B) tile, BK=64, SINGLE-buffered 32KB LDS, 2 barriers/step:
//   sync(a); writeB(t); stageA(t); sync(drain); issue loadB(t+1); compute(t)
// B(t+1) HBM latency hides under compute(t); 32KB LDS -> 3-5 blocks/CU so the
// per-step drain stall is covered by co-resident blocks (m114 mechanism).
// EPI 0 (DUAL): Cb = bf16( silu(acc1) * acc3 )
// EPI 1: C0 = acc1 (f32 store)
// EPI 2: atomicAdd(C0[perm[row]*ldc0+col], acc1 * pwt[row]) for valid rows
template <bool GATHER, bool DUAL, int EPI>
__global__ __launch_bounds__(256) void gemm5_kernel(
    const u16* __restrict__ A, int lda,
    const float* __restrict__ B1, const float* __restrict__ B3,
    int ldb, long bstride, int K,
    const int* __restrict__ tile2e, const int* __restrict__ tile2m0,
    const int* __restrict__ seg_off, const int* __restrict__ seg_cnt,
    const int* __restrict__ perm, const float* __restrict__ pwt,
    float* __restrict__ C0, int ldc0,
    u16* __restrict__ Cb, int ldcb, int Mfixed) {
  int e, m0, rowlim;
  if (tile2e) {
    e = tile2e[blockIdx.x];
    if (e < 0) return;                 // empty remap slot
    m0 = tile2m0[blockIdx.x];
    rowlim = seg_off[e] + seg_cnt[e];
  } else {
    e = 0;
    m0 = blockIdx.x * 128;
    if (m0 >= Mfixed) return;
    rowlim = Mfixed;
  }
  int n0 = blockIdx.y * 64;
  const float* Bb1 = B1 + (long)e * bstride;
  const float* Bb3 = DUAL ? (B3 + (long)e * bstride) : nullptr;

  __shared__ u16 As[128 * 64];                 // 16 KB
  __shared__ u16 Bs1[64 * 64];                 // 8 KB
  __shared__ u16 Bs3[DUAL ? 64 * 64 : 1];      // 8 KB if DUAL

  int tid = threadIdx.x;
  int lane = tid & 63;
  int wid = tid >> 6;
  int wr = wid >> 1, wc = wid & 1;

  f32x4 acc1[4][2], acc3[4][2];
#pragma unroll
  for (int mi = 0; mi < 4; ++mi)
#pragma unroll
    for (int ni = 0; ni < 2; ++ni) {
      acc1[mi][ni] = (f32x4){0.f, 0.f, 0.f, 0.f};
      acc3[mi][ni] = (f32x4){0.f, 0.f, 0.f, 0.f};
    }

  // A staging: thread -> 16B chunk; LDS dest wave-uniform base + lane*16 (linear)
  int ar = tid >> 3;          // 0..31
  int ac = (tid & 7) * 8;     // bf16 col
  long abase[4];
#pragma unroll
  for (int it = 0; it < 4; ++it) {
    int row = m0 + it * 32 + ar;
    int rid = GATHER ? perm[row] : row;
    abase[it] = (long)rid * lda + ac;
  }
  // B staging: 64 rows x 64 f32 per matrix; thread -> 4 float4 per matrix
  int brr = tid >> 4;         // 0..15
  int bsl = (tid & 15) * 4;   // f32 col
  long bbase[4];
#pragma unroll
  for (int it = 0; it < 4; ++it)
    bbase[it] = (long)(n0 + it * 16 + brr) * ldb + bsl;

  float4 r1[4], r3[4];

  auto stageA = [&](int k0) {
#pragma unroll
    for (int it = 0; it < 4; ++it)
      gload_lds16(A + abase[it] + k0, &As[(it * 32 + ar) * 64 + ac]);
  };
  auto loadB = [&](int k0) {
#pragma unroll
    for (int it = 0; it < 4; ++it) r1[it] = *(const float4*)(Bb1 + bbase[it] + k0);
    if (DUAL) {
#pragma unroll
      for (int it = 0; it < 4; ++it) r3[it] = *(const float4*)(Bb3 + bbase[it] + k0);
    }
  };
  auto writeB = [&]() {
#pragma unroll
    for (int it = 0; it < 4; ++it) {
      int lo = (it * 16 + brr) * 64 + bsl;
      ushort4 o;
      o.x = f2bf(r1[it].x); o.y = f2bf(r1[it].y); o.z = f2bf(r1[it].z); o.w = f2bf(r1[it].w);
      *(ushort4*)&Bs1[lo] = o;
      if (DUAL) {
        ushort4 q;
        q.x = f2bf(r3[it].x); q.y = f2bf(r3[it].y); q.z = f2bf(r3[it].z); q.w = f2bf(r3[it].w);
        *(ushort4*)&Bs3[lo] = q;
      }
    }
  };

  loadB(0);                       // prologue: B(0) -> regs
  int NT = K >> 6;
  for (int t = 0; t < NT; ++t) {
    if (t) __syncthreads();       // (a) all waves done reading LDS(t-1)
    stageA(t << 6);               // async A(t) -> LDS
    writeB();                     // regs B(t) -> LDS (bf16)
    __syncthreads();              // (b) drain: As,Bs ready
    if (t + 1 < NT) loadB((t + 1) << 6);   // issue B(t+1); completes under compute
#pragma unroll
    for (int kk = 0; kk < 64; kk += 32) {
      short8 af[4], b1f[2], b3f[2];
#pragma unroll
      for (int i = 0; i < 4; ++i)
        af[i] = *(const short8*)&As[(wr * 64 + i * 16 + (lane & 15)) * 64 + kk + (lane >> 4) * 8];
#pragma unroll
      for (int i = 0; i < 2; ++i)
        b1f[i] = *(const short8*)&Bs1[(wc * 32 + i * 16 + (lane & 15)) * 64 + kk + (lane >> 4) * 8];
      if (DUAL) {
#pragma unroll
        for (int i = 0; i < 2; ++i)
          b3f[i] = *(const short8*)&Bs3[(wc * 32 + i * 16 + (lane & 15)) * 64 + kk + (lane >> 4) * 8];
      }
#pragma unroll
      for (int mi = 0; mi < 4; ++mi)
#pragma unroll
        for (int ni = 0; ni < 2; ++ni) {
          acc1[mi][ni] = __builtin_amdgcn_mfma_f32_16x16x32_bf16(af[mi], b1f[ni], acc1[mi][ni], 0, 0, 0);
          if (DUAL)
            acc3[mi][ni] = __builtin_amdgcn_mfma_f32_16x16x32_bf16(af[mi], b3f[ni], acc3[mi][ni], 0, 0, 0);
        }
    }
  }

  int rbase = m0 + wr * 64 + (lane >> 4) * 4;
  int cbase = n0 + wc * 32 + (lane & 15);
#pragma unroll
  for (int mi = 0; mi < 4; ++mi) {
#pragma unroll
    for (int ni = 0; ni < 2; ++ni) {
      int col = cbase + ni * 16;
#pragma unroll
      for (int r = 0; r < 4; ++r) {
        int row = rbase + mi * 16 + r;
        float v = acc1[mi][ni][r];
        if (EPI == 0) {
          float a3 = acc3[mi][ni][r];
          float sg = v / (1.f + __expf(-v));
          Cb[(long)row * ldcb + col] = f2bf(sg * a3);
        } else if (EPI == 1) {
          C0[(long)row * ldc0 + col] = v;
        } else {
          if (row < rowlim) {
            atomicAdd(&C0[(long)perm[row] * ldc0 + col], v * pwt[row]);
          }
        }
      }
    }
  }
}

extern "C" void kernel_launch(void* const* d_in, const int* in_sizes, int n_in,
                              void* d_out, int out_size, void* d_ws, size_t ws_size,
                              hipStream_t stream) {
  (void)in_sizes; (void)n_in; (void)out_size; (void)ws_size;
  const float* x   = (const float*)d_in[0];
  const float* gw  = (const float*)d_in[1];
  const float* w1  = (const float*)d_in[2];
  const float* w2  = (const float*)d_in[3];
  const float* w3  = (const float*)d_in[4];
  const float* sw1 = (const float*)d_in[5];
  const float* sw2 = (const float*)d_in[6];
  const float* sw3 = (const float*)d_in[7];
  float* out = (float*)d_out;
  char* ws = (char*)d_ws;

  int*   counts = (int*)(ws + 0);
  int*   cursor = (int*)(ws + 64);
  int*   off    = (int*)(ws + 128);
  int*   cap    = (int*)(ws + 192);
  float* ssum   = (float*)(ws + 256);
  int*   tile2e = (int*)(ws + 1024);
  int*   tile2m0= (int*)(ws + 2048);
  int*   idxb   = (int*)(ws + 4096);
  float* wtb    = (float*)(ws + 4096 + 32768);
  int*   perm   = (int*)(ws + 4096 + 65536);
  float* pwt    = (float*)(ws + 4096 + 65536 + 40960);
  u16*   xb     = (u16*)(ws + 262144);                 // 2048x2048 bf16, 8.39 MB
  double* logits = (double*)(ws + 8650752);            // 2048x16 f64
  u16*   hbuf   = (u16*)(ws + 16777216);               // 10240x1408 bf16, 28.8 MB
  u16*   hsb    = (u16*)(ws + 45613056);               // 2048x2816 bf16, 11.5 MB

  hipMemsetAsync(ws, 0, 512, stream);
  gate_dots_kernel<<<dim3(NTOK), dim3(256), 0, stream>>>(x, gw, logits);
  topk_kernel<<<dim3(NTOK / 256), dim3(256), 0, stream>>>(logits, idxb, wtb, counts, ssum);
  setup_kernel<<<dim3(1), dim3(256), 0, stream>>>(counts, off, cap, ssum, perm, pwt,
                                                  out + AUX_IDX, tile2e, tile2m0);
  scatter_kernel<<<dim3(8), dim3(256), 0, stream>>>(idxb, wtb, off, cursor, perm, pwt);
  cvtN_kernel<<<dim3(2048), dim3(256), 0, stream>>>(x, xb, (long)NTOK * DIM);

  // routed h = silu(gather(x)@w1^T) * (gather(x)@w3^T) -> bf16  [dual-B, f32 weights direct]
  gemm5_kernel<true, true, 0><<<dim3(MAXTILES, HID / 64, 1), dim3(256), 0, stream>>>(
      xb, DIM, w1, w3, DIM, (long)HID * DIM, DIM, tile2e, tile2m0,
      off, counts, perm, pwt, nullptr, 0, hbuf, HID, 0);
  // shared hs = silu(x@sw1^T) * (x@sw3^T) -> bf16
  gemm5_kernel<false, true, 0><<<dim3(NTOK / 128, SHID / 64, 1), dim3(256), 0, stream>>>(
      xb, DIM, sw1, sw3, DIM, 0, DIM, nullptr, nullptr,
      nullptr, nullptr, nullptr, nullptr, nullptr, 0, hsb, SHID, NTOK);
  // z = hs @ sw2^T  (f32 store into out)
  gemm5_kernel<false, false, 1><<<dim3(NTOK / 128, DIM / 64, 1), dim3(256), 0, stream>>>(
      hsb, SHID, sw2, nullptr, SHID, 0, SHID, nullptr, nullptr,
      nullptr, nullptr, nullptr, nullptr, out, DIM, nullptr, 0, NTOK);
  // out += (h @ w2^T) * pwt
  gemm5_kernel<false, false, 2><<<dim3(MAXTILES, DIM / 64, 1), dim3(256), 0, stream>>>(
      hbuf, HID, w2, nullptr, HID, (long)DIM * HID, HID, tile2e, tile2m0,
      off, counts, perm, pwt, out, DIM, nullptr, 0, 0);
}